// Round 15
// baseline (246.501 us; speedup 1.0000x reference)
//
#include <hip/hip_runtime.h>

// ---------------- problem constants ----------------
#define G_DIM 3072
#define P_DIM 1024
#define ALPHA 0.1f

typedef __attribute__((ext_vector_type(8))) __bf16 bf16x8;
typedef __attribute__((ext_vector_type(4))) float  f32x4;

// ---- memory plan ----
// ws: X = [0, 50.3M) bf16 [8192][3072] (row = rr*2+c), W = [50.3M, 69.2M)
// d_out doubles as scratch before the propagate overwrites every element:
//   S = d_out[0,18.9M), St = d_out[18.9M,37.7M)
#define GG2      ((size_t)G_DIM * G_DIM * 2)          // 18,874,368 B
#define XBYTES   ((size_t)8192 * G_DIM * 2)           // 50,331,648 B

// ---- softmax + gg-channel deinterleave fused ----
__global__ __launch_bounds__(256) void row_softmax_k(const float* __restrict__ gg,
                                                     __bf16* __restrict__ S,
                                                     __bf16* __restrict__ X) {
  const int i = blockIdx.x;
  const float* row = gg + (size_t)i * G_DIM * 2;  // [G][2]
  const int tid = threadIdx.x;
  const int lane = tid & 63, wave = tid >> 6;

  float2 p[12];
  float v[12];
  float m = -INFINITY;
#pragma unroll
  for (int t = 0; t < 12; ++t) {
    int j = tid + t * 256;
    p[t] = ((const float2*)row)[j];
    float x = p[t].y;
    if (j == i) x = -INFINITY;
    v[t] = x;
    m = fmaxf(m, x);
  }

  // write X gg-rows (raw scores, both channels)
  {
    __bf16* x0 = X + (size_t)(2048 + 2 * i) * G_DIM;
    __bf16* x1 = x0 + G_DIM;
#pragma unroll
    for (int t = 0; t < 12; ++t) {
      int j = tid + t * 256;
      x0[j] = (__bf16)p[t].x;
      x1[j] = (__bf16)p[t].y;
    }
  }

#pragma unroll
  for (int o = 32; o; o >>= 1) m = fmaxf(m, __shfl_xor(m, o));
  __shared__ float red[4];
  if (lane == 0) red[wave] = m;
  __syncthreads();
  m = fmaxf(fmaxf(red[0], red[1]), fmaxf(red[2], red[3]));

  float s = 0.f;
#pragma unroll
  for (int t = 0; t < 12; ++t) {
    v[t] = __expf(v[t] - m);
    s += v[t];
  }
#pragma unroll
  for (int o = 32; o; o >>= 1) s += __shfl_xor(s, o);
  __syncthreads();
  if (lane == 0) red[wave] = s;
  __syncthreads();
  s = red[0] + red[1] + red[2] + red[3];

  const float scale = ALPHA / s;
  __bf16* out = S + (size_t)i * G_DIM;
#pragma unroll
  for (int t = 0; t < 12; ++t) {
    int j = tid + t * 256;
    out[j] = (__bf16)(v[t] * scale);
  }
}

// ---------------- bf16 transpose ----------------
__global__ void transpose_k(const __bf16* __restrict__ in, __bf16* __restrict__ out) {
  __shared__ __bf16 t[32][33];
  const int bx = blockIdx.x * 32, by = blockIdx.y * 32;
  const int tx = threadIdx.x, ty = threadIdx.y;
#pragma unroll
  for (int k = 0; k < 32; k += 8)
    t[ty + k][tx] = in[(size_t)(by + ty + k) * G_DIM + bx + tx];
  __syncthreads();
#pragma unroll
  for (int k = 0; k < 32; k += 8)
    out[(size_t)(bx + ty + k) * G_DIM + by + tx] = t[tx][ty + k];
}

// ---- pg-only deinterleave into X rows 0..2047 ----
__global__ __launch_bounds__(384) void deinterleave_pg_k(const float* __restrict__ pg,
                                                         __bf16* __restrict__ X) {
  const int rr = blockIdx.x;  // 0..1023
  const float* src = pg + (size_t)rr * G_DIM * 2;
  const int t = threadIdx.x;
  const float4* s4 = (const float4*)(src + (size_t)t * 16);
  float4 a = s4[0], b = s4[1], c = s4[2], d = s4[3];
  bf16x8 v0, v1;
  v0[0] = (__bf16)a.x; v1[0] = (__bf16)a.y;
  v0[1] = (__bf16)a.z; v1[1] = (__bf16)a.w;
  v0[2] = (__bf16)b.x; v1[2] = (__bf16)b.y;
  v0[3] = (__bf16)b.z; v1[3] = (__bf16)b.w;
  v0[4] = (__bf16)c.x; v1[4] = (__bf16)c.y;
  v0[5] = (__bf16)c.z; v1[5] = (__bf16)c.w;
  v0[6] = (__bf16)d.x; v1[6] = (__bf16)d.y;
  v0[7] = (__bf16)d.z; v1[7] = (__bf16)d.w;
  *(bf16x8*)(X + (size_t)(rr * 2) * G_DIM + t * 8)     = v0;
  *(bf16x8*)(X + (size_t)(rr * 2 + 1) * G_DIM + t * 8) = v1;
}

// ------- one staged global->LDS chunk (1 KiB), pre-swizzled source (rule #21) -------
__device__ __forceinline__ void stage1(const __bf16* __restrict__ src, size_t row0,
                                       int K, int k0, char* ldsbase, int chunk, int lane) {
  int Lb = chunk << 10;                   // wave-uniform LDS byte base
  int L  = Lb + lane * 16;                // this lane's dest byte
  int r  = L >> 7;                        // region row
  int slot = ((L >> 4) & 7) ^ (r & 7);    // inverse swizzle on SOURCE
  const __bf16* g = src + (row0 + (size_t)r) * (size_t)K + (size_t)(k0 + slot * 8);
  __builtin_amdgcn_global_load_lds((const __attribute__((address_space(1))) void*)g,
                                   (__attribute__((address_space(3))) void*)(ldsbase + Lb),
                                   16, 0, 0);
}

#define MFMA16(a, b, c) __builtin_amdgcn_mfma_f32_16x16x32_bf16((a), (b), (c), 0, 0, 0)
#define LDS_RD(base, row, xx) (*(const bf16x8*)((base) + (size_t)(row) * 128 + (xx)))
#define LGKM0()  asm volatile("s_waitcnt lgkmcnt(0)" ::: "memory")
#define VM3()    asm volatile("s_waitcnt vmcnt(3)" ::: "memory")
#define VM0()    asm volatile("s_waitcnt vmcnt(0)" ::: "memory")
#define BAR()    __builtin_amdgcn_s_barrier()
#define PRIO(x)  __builtin_amdgcn_s_setprio(x)
#define FENCE()  asm volatile("" ::: "memory")

// ======== PROPAGATE: 256x192 NT GEMM, 3 phases / K-tile, 4Mx2N wave layout ========
// Change vs R7/R9/R14: waves arranged 4M x 2N -> wave tile 64x96, acc[4][6].
// LDS-read bytes/FLOP drops 9% (20 vs 22 ds_read_b128 / wave / K-tile); staging,
// barrier ledger, and accumulation order are UNCHANGED (bitwise-identical output).
// Phases: ph1 {stage A0'; read av(8)+bv01(4); MFMA nf0-1}, ph2 {stage A1';
// read bv2345(8); MFMA nf2-3 (bv45 stays in flight = prefetch)}, LGKM0, BAR#1,
// ph3 {stage B''; MFMA nf4-5; gate vmcnt; BAR#2}.
__global__ __launch_bounds__(512, 2) void gemm3p(const __bf16* __restrict__ A,
                                                 const __bf16* __restrict__ B,
                                                 void* __restrict__ C,
                                                 const float* __restrict__ pgin,
                                                 const float* __restrict__ ggin,
                                                 int M, int N, int K) {
  __shared__ char lds[114688];   // 2 x (32 KiB A + 24 KiB B)

  const int tid = threadIdx.x;
  const int wave = tid >> 6, lane = tid & 63;
  const int wm = wave >> 1, wn = wave & 1;   // 4M x 2N
  const int lr = lane & 15, g4 = lane >> 4;

  const size_t arow0 = (size_t)blockIdx.x * 256;   // bx = M-tile
  const size_t brow0 = (size_t)blockIdx.y * 192;

  f32x4 acc[4][6] = {};
  const int NT = K / 64;

  const int a2w = wave * 2;
  const int b3w = wave * 3;
  const int x0 = ((g4) ^ (lr & 7)) * 16;
  const int x1 = ((4 + g4) ^ (lr & 7)) * 16;
  // this wave's A rows: wm*64 + mf*16 + lr; A stored as two 128-row halves
  const int ahalf = (wm >> 1) * 16384;            // byte offset of A half
  const int arow  = (wm & 1) * 64 + lr;           // row within half (+ mf*16)
  const int brow  = wn * 96 + lr;                 // B row (+ nf*16)

  // prologue: tile0 {A0,A1,B} + tile1 {B}
  {
    char* b0 = lds;
    char* b1 = lds + 57344;
    stage1(A, arow0,       K, 0,  b0,         a2w, lane);
    stage1(A, arow0,       K, 0,  b0,         a2w + 1, lane);
    stage1(A, arow0 + 128, K, 0,  b0 + 16384, a2w, lane);
    stage1(A, arow0 + 128, K, 0,  b0 + 16384, a2w + 1, lane);
    stage1(B, brow0,       K, 0,  b0 + 32768, b3w, lane);
    stage1(B, brow0,       K, 0,  b0 + 32768, b3w + 1, lane);
    stage1(B, brow0,       K, 0,  b0 + 32768, b3w + 2, lane);
    stage1(B, brow0,       K, 64, b1 + 32768, b3w, lane);
    stage1(B, brow0,       K, 64, b1 + 32768, b3w + 1, lane);
    stage1(B, brow0,       K, 64, b1 + 32768, b3w + 2, lane);
  }
  VM3();
  BAR();

  for (int t = 0; t < NT; ++t) {
    char* buf = lds + (t & 1) * 57344;
    char* nxt = lds + ((t + 1) & 1) * 57344;
    char* Ab = buf + ahalf;
    char* Bb = buf + 32768;
    const int kn = (t + 1) * 64;
    const int k2 = (t + 2) * 64;
    const bool pa = (t + 1) < NT;
    const bool pb = (t + 2) < NT;

    bf16x8 av[4][2], bv01[2][2], bv23[2][2], bv45[2][2];

    // ---- ph1: stage A0_{t+1}; read av(8) + bv01(4); MFMA nf0-1 (16) ----
    if (pa) {
      stage1(A, arow0, K, kn, nxt, a2w, lane);
      stage1(A, arow0, K, kn, nxt, a2w + 1, lane);
    }
#pragma unroll
    for (int mf = 0; mf < 4; ++mf) {
      av[mf][0] = LDS_RD(Ab, arow + mf * 16, x0);
      av[mf][1] = LDS_RD(Ab, arow + mf * 16, x1);
    }
#pragma unroll
    for (int nf = 0; nf < 2; ++nf) {
      bv01[nf][0] = LDS_RD(Bb, brow + nf * 16, x0);
      bv01[nf][1] = LDS_RD(Bb, brow + nf * 16, x1);
    }
    PRIO(1);
#pragma unroll
    for (int mf = 0; mf < 4; ++mf)
#pragma unroll
      for (int nf = 0; nf < 2; ++nf)
#pragma unroll
        for (int ks = 0; ks < 2; ++ks)
          acc[mf][nf] = MFMA16(av[mf][ks], bv01[nf][ks], acc[mf][nf]);
    PRIO(0);

    // ---- ph2: stage A1_{t+1}; read bv2345(8); MFMA nf2-3 (16) ----
    if (pa) {
      stage1(A, arow0 + 128, K, kn, nxt + 16384, a2w, lane);
      stage1(A, arow0 + 128, K, kn, nxt + 16384, a2w + 1, lane);
    }
#pragma unroll
    for (int nf = 0; nf < 2; ++nf) {
      bv23[nf][0] = LDS_RD(Bb, brow + 32 + nf * 16, x0);
      bv23[nf][1] = LDS_RD(Bb, brow + 32 + nf * 16, x1);
      bv45[nf][0] = LDS_RD(Bb, brow + 64 + nf * 16, x0);
      bv45[nf][1] = LDS_RD(Bb, brow + 64 + nf * 16, x1);
    }
    PRIO(1);
#pragma unroll
    for (int mf = 0; mf < 4; ++mf)
#pragma unroll
      for (int nf = 0; nf < 2; ++nf)
#pragma unroll
        for (int ks = 0; ks < 2; ++ks)
          acc[mf][2 + nf] = MFMA16(av[mf][ks], bv23[nf][ks], acc[mf][2 + nf]);
    PRIO(0);
    LGKM0();
    BAR();     // BAR#1: all reads of buf complete -> safe to overwrite buf.B

    // ---- ph3: stage B_{t+2} -> buf; MFMA nf4-5 (16); gate; BAR#2 ----
    if (pb) {
      stage1(B, brow0, K, k2, Bb, b3w, lane);
      stage1(B, brow0, K, k2, Bb, b3w + 1, lane);
      stage1(B, brow0, K, k2, Bb, b3w + 2, lane);
    }
    PRIO(1);
#pragma unroll
    for (int mf = 0; mf < 4; ++mf)
#pragma unroll
      for (int nf = 0; nf < 2; ++nf)
#pragma unroll
        for (int ks = 0; ks < 2; ++ks)
          acc[mf][4 + nf] = MFMA16(av[mf][ks], bv45[nf][ks], acc[mf][4 + nf]);
    PRIO(0);
    if (t >= NT - 2) VM0(); else VM3();
    BAR();     // BAR#2
  }

  // epilogue — C/D layout: col = lane&15, row = (lane>>4)*4 + reg
  const int r0 = (int)arow0 + wm * 64;
  const int c0 = (int)brow0 + wn * 96;
#pragma unroll
  for (int mf = 0; mf < 4; ++mf) {
#pragma unroll
    for (int nf = 0; nf < 6; ++nf) {
      const int col = c0 + nf * 16 + lr;
#pragma unroll
      for (int jp = 0; jp < 2; ++jp) {
        const int row = r0 + mf * 16 + g4 * 4 + jp * 2;  // even
        const int rr = row >> 1;
        const size_t base = (size_t)rr * G_DIM * 2 + (size_t)col * 2;
        const float* src = (rr < P_DIM) ? (pgin + base)
                                        : (ggin + base - (size_t)P_DIM * G_DIM * 2);
        float2 sv = *(const float2*)src;
        float2 ov;
        ov.x = acc[mf][nf][jp * 2]     + 0.9f * sv.x;
        ov.y = acc[mf][nf][jp * 2 + 1] + 0.9f * sv.y;
        *(float2*)((float*)C + base) = ov;
      }
    }
  }
  (void)M;
}

// ======== W-GEMM: 192x192 NT, one barrier / K-tile, A dbuf + B ring-3 (R8) ========
__global__ __launch_bounds__(512, 2) void gemmW(const __bf16* __restrict__ A,
                                                const __bf16* __restrict__ B,
                                                __bf16* __restrict__ C,
                                                const __bf16* __restrict__ e0,
                                                int N, int K) {
  constexpr int MF     = 6;
  constexpr int BM     = MF * 32;       // 192
  constexpr int ABYTES = BM * 128;      // 24576
  constexpr int ACH    = BM / 64;       // 3
  __shared__ char lds[2 * ABYTES + 3 * 24576];

  const int tid = threadIdx.x;
  const int wave = tid >> 6, lane = tid & 63;
  const int wm = wave >> 2, wn = wave & 3;   // 2M x 4N
  const int lr = lane & 15, g4 = lane >> 4;

  const size_t arow0 = (size_t)blockIdx.x * BM;
  const size_t brow0 = (size_t)blockIdx.y * 192;

  f32x4 acc[MF][3] = {};
  const int NT = K / 64;

  const int x0 = ((g4) ^ (lr & 7)) * 16;
  const int x1 = ((4 + g4) ^ (lr & 7)) * 16;
  const int arbase = wm * (MF * 16);

  {
    char* A0 = lds;
    char* B0 = lds + 2 * ABYTES;
    char* B1 = B0 + 24576;
#pragma unroll
    for (int q = 0; q < ACH; ++q) stage1(A, arow0, K, 0,  A0, wave * ACH + q, lane);
#pragma unroll
    for (int q = 0; q < 3; ++q)   stage1(B, brow0, K, 0,  B0, wave * 3 + q, lane);
#pragma unroll
    for (int q = 0; q < 3; ++q)   stage1(B, brow0, K, 64, B1, wave * 3 + q, lane);
  }

  for (int t = 0; t < NT; ++t) {
    char* Abuf = lds + (t & 1) * ABYTES;
    char* Anxt = lds + ((t + 1) & 1) * ABYTES;
    char* Bbuf = lds + 2 * ABYTES + (t % 3) * 24576;
    char* Bst  = lds + 2 * ABYTES + ((t + 2) % 3) * 24576;

    if (t == NT - 1) VM0(); else VM3();
    BAR();
    FENCE();

    if (t + 1 < NT) {
#pragma unroll
      for (int q = 0; q < ACH; ++q)
        stage1(A, arow0, K, (t + 1) * 64, Anxt, wave * ACH + q, lane);
    }
    if (t + 2 < NT) {
#pragma unroll
      for (int q = 0; q < 3; ++q)
        stage1(B, brow0, K, (t + 2) * 64, Bst, wave * 3 + q, lane);
    }

    bf16x8 av[MF][2], bv[3][2];
#pragma unroll
    for (int mf = 0; mf < MF; ++mf) {
      av[mf][0] = LDS_RD(Abuf, arbase + mf * 16 + lr, x0);
      av[mf][1] = LDS_RD(Abuf, arbase + mf * 16 + lr, x1);
    }
#pragma unroll
    for (int nf = 0; nf < 3; ++nf) {
      bv[nf][0] = LDS_RD(Bbuf, wn * 48 + nf * 16 + lr, x0);
      bv[nf][1] = LDS_RD(Bbuf, wn * 48 + nf * 16 + lr, x1);
    }
    PRIO(1);
#pragma unroll
    for (int mf = 0; mf < MF; ++mf)
#pragma unroll
      for (int nf = 0; nf < 3; ++nf)
#pragma unroll
        for (int ks = 0; ks < 2; ++ks)
          acc[mf][nf] = MFMA16(av[mf][ks], bv[nf][ks], acc[mf][nf]);
    PRIO(0);
    LGKM0();
  }

  const int r0 = (int)arow0 + arbase;
  const int c0 = (int)brow0 + wn * 48;
#pragma unroll
  for (int mf = 0; mf < MF; ++mf) {
#pragma unroll
    for (int nf = 0; nf < 3; ++nf) {
      const int col = c0 + nf * 16 + lr;
#pragma unroll
      for (int jj = 0; jj < 4; ++jj) {
        const int row = r0 + mf * 16 + g4 * 4 + jj;
        float w = 0.9f * (acc[mf][nf][jj] + (float)e0[(size_t)row * N + col]);
        C[(size_t)row * N + col] = (__bf16)w;
      }
    }
  }
}

// ---------------- launch ----------------
extern "C" void kernel_launch(void* const* d_in, const int* in_sizes, int n_in,
                              void* d_out, int out_size, void* d_ws, size_t ws_size,
                              hipStream_t stream) {
  const float* pg = (const float*)d_in[0];  // [P,G,2] f32
  const float* gg = (const float*)d_in[1];  // [G,G,2] f32
  float* out = (float*)d_out;

  char* ws = (char*)d_ws;
  __bf16* X  = (__bf16*)ws;                        // [0, 50.3M)
  __bf16* W  = (__bf16*)(ws + XBYTES);             // [50.3M, 69.2M)
  __bf16* S  = (__bf16*)d_out;                     // d_out scratch [0, 18.9M)
  __bf16* St = (__bf16*)((char*)d_out + GG2);      // d_out scratch [18.9M, 37.7M)

  // 1. S = alpha*softmax(gg ch1, -inf diag); ALSO writes X gg-rows (fused)
  row_softmax_k<<<G_DIM, 256, 0, stream>>>(gg, S, X);
  // 2. St = S^T
  transpose_k<<<dim3(96, 96), dim3(32, 8), 0, stream>>>(S, St);
  // 3. W = 0.9*(S*S + S)   (192x192 tile -> 256 blocks = exactly 1 CU round)
  gemmW<<<dim3(16, 16), 512, 0, stream>>>(S, St, W, S, G_DIM, G_DIM);
  // 4. X pg-rows only (gg rows already written by softmax)
  deinterleave_pg_k<<<P_DIM, 384, 0, stream>>>(pg, X);
  // 5. out = X * W^T + 0.9 * X_f32  (overwrites the S/St scratch in d_out)
  gemm3p<<<dim3(32, 16), 512, 0, stream>>>(X, W, out, pg, gg, 8192, G_DIM, G_DIM);
  (void)in_sizes; (void)n_in; (void)out_size; (void)ws_size;
}